// Round 8
// baseline (202.054 us; speedup 1.0000x reference)
//
#include <hip/hip_runtime.h>

#define L_SEQ 4096

typedef unsigned short u16;
typedef unsigned int u32;
typedef __bf16 bf16_t;
typedef bf16_t bf16x8 __attribute__((ext_vector_type(8)));
typedef float f32x4 __attribute__((ext_vector_type(4)));
typedef float f32x2 __attribute__((ext_vector_type(2)));
typedef unsigned short u16x8 __attribute__((ext_vector_type(8)));
typedef unsigned short u16x4 __attribute__((ext_vector_type(4)));

__device__ __forceinline__ u16 f2b(float f) {
  unsigned u = __float_as_uint(f);
  u += 0x7fffu + ((u >> 16) & 1u);   // RNE
  return (u16)(u >> 16);
}
__device__ __forceinline__ float b2f(u16 b) {
  return __uint_as_float(((unsigned)b) << 16);
}

#define FENCE asm volatile("" ::: "memory")
#define BARRIER __builtin_amdgcn_s_barrier()
#define WAIT_LGKM0 asm volatile("s_waitcnt lgkmcnt(0)" ::: "memory")
#define WAIT_VM4 asm volatile("s_waitcnt vmcnt(4)" ::: "memory")
#define SB0 __builtin_amdgcn_sched_barrier(0)
#define AS1 __attribute__((address_space(1)))
#define AS3 __attribute__((address_space(3)))

// ---------------- fused prep: x->bf16 cvt + both weight transposes ----------------
// blocks [0,4096): cvt 16 elems/thread; [4096,7168): w_qkv^T; [7168,8192): w_proj^T
__global__ __launch_bounds__(256) void k_prep(const float* __restrict__ x,
                                              u16* __restrict__ xb,
                                              const float* __restrict__ wq,
                                              u16* __restrict__ wqT,
                                              const float* __restrict__ wp,
                                              u16* __restrict__ wpT) {
  const int bid = blockIdx.x;
  const int t = threadIdx.x;
  if (bid < 4096) {
    const int i = (bid * 256 + t) * 16;
    f32x4 v0 = *reinterpret_cast<const f32x4*>(x + i);
    f32x4 v1 = *reinterpret_cast<const f32x4*>(x + i + 4);
    f32x4 v2 = *reinterpret_cast<const f32x4*>(x + i + 8);
    f32x4 v3 = *reinterpret_cast<const f32x4*>(x + i + 12);
    u16x8 o0, o1;
#pragma unroll
    for (int j = 0; j < 4; ++j) {
      o0[j] = f2b(v0[j]); o0[4 + j] = f2b(v1[j]);
      o1[j] = f2b(v2[j]); o1[4 + j] = f2b(v3[j]);
    }
    *reinterpret_cast<u16x8*>(xb + i) = o0;
    *reinterpret_cast<u16x8*>(xb + i + 8) = o1;
    return;
  }
  // transpose path: fp32 [R][C] -> bf16 [C][R]
  const float* in; u16* out; int R, C, bx, by;
  if (bid < 7168) {
    const int b2 = bid - 4096;             // 96 x 32 tiles
    in = wq; out = wqT; R = 1024; C = 3072;
    bx = (b2 % 96) * 32; by = (b2 / 96) * 32;
  } else {
    const int b2 = bid - 7168;             // 32 x 32 tiles
    in = wp; out = wpT; R = 1024; C = 1024;
    bx = (b2 % 32) * 32; by = (b2 / 32) * 32;
  }
  __shared__ float tile[32][33];
  const int tx = t & 31, ty = t >> 5;      // (32,8)
#pragma unroll
  for (int i = 0; i < 32; i += 8)
    tile[ty + i][tx] = in[(size_t)(by + ty + i) * C + (bx + tx)];
  __syncthreads();
#pragma unroll
  for (int i = 0; i < 32; i += 8)
    out[(size_t)(bx + ty + i) * R + (by + tx)] = f2b(tile[tx][ty + i]);
}

// ---------------- persistent 256x256 8-phase bf16 GEMM ----------------
// Row-major tile order (round-6 proven). Lane-pair-packed C epilogue.
template <bool OUT_BF16>
__global__ __launch_bounds__(512, 2) void k_gemm256p(const u16* __restrict__ A,
                                                     const u16* __restrict__ Bt,
                                                     void* __restrict__ Cv,
                                                     int M, int N, int K,
                                                     int ntiles, int gx) {
  __shared__ __align__(16) char lds[131072];
  const int tid = threadIdx.x;
  const int wid = tid >> 6, lane = tid & 63;
  const int wm = wid >> 2, wn = wid & 3;      // 2x4 wave grid
  const int lr = lane & 15, lq = lane >> 4;
  const int xr = (lr & 7) << 4;               // read-side XOR swizzle
  const int koff0 = (lq * 16) ^ xr;
  const int koff1 = (64 | (lq * 16)) ^ xr;

  const int cpx = 32 * ntiles;                // (256*ntiles)/8
  auto tilecoord = [&](int ff, int& mm, int& nn) {
    int swz = (ff & 7) * cpx + (ff >> 3);
    mm = (swz / gx) * 256; nn = (swz % gx) * 256;
  };

  // per-thread staging constants (source pre-swizzled to match swizzled reads)
  const int rowT = tid >> 3;                                        // 0..63
  const int colT = (((tid * 16) & 127) ^ ((rowT & 7) << 4)) >> 1;   // u16 units
  const size_t r64K = (size_t)64 * K;
  const size_t r128K = (size_t)128 * K;

  int m0, n0;
  tilecoord(blockIdx.x, m0, n0);
  const u16* pAc = A + (size_t)(m0 + rowT) * K + colT;
  const u16* pBc = Bt + (size_t)(n0 + rowT) * K + colT;

  f32x4 acc[8][4];
  bf16x8 a[4][2];
  bf16x8 bb[2][2][2];

  auto STG = [&](const u16* bp, int region, size_t hoff, int k0) {
    const u16* s0 = bp + hoff + k0;
    __builtin_amdgcn_global_load_lds((const AS1 void*)s0,
                                     (AS3 void*)(lds + region + wid * 1024), 16, 0, 0);
    __builtin_amdgcn_global_load_lds((const AS1 void*)(s0 + r64K),
                                     (AS3 void*)(lds + region + 8192 + wid * 1024), 16, 0, 0);
  };
  auto rdA = [&](int dbuf, int mh) {
#pragma unroll
    for (int mi = 0; mi < 4; ++mi) {
      const int base = dbuf * 65536 + wm * 16384 + (mh * 64 + mi * 16 + lr) * 128;
      a[mi][0] = *(const bf16x8*)(lds + base + koff0);
      a[mi][1] = *(const bf16x8*)(lds + base + koff1);
    }
  };
  auto rdB = [&](int dbuf, int nh, int bset) {
#pragma unroll
    for (int ni = 0; ni < 2; ++ni) {
      const int base = dbuf * 65536 + 32768 + (wn >> 1) * 16384 +
                       ((wn & 1) * 64 + nh * 32 + ni * 16 + lr) * 128;
      bb[bset][ni][0] = *(const bf16x8*)(lds + base + koff0);
      bb[bset][ni][1] = *(const bf16x8*)(lds + base + koff1);
    }
  };
  auto mfma16 = [&](int mh, int nh, int bset) {
    __builtin_amdgcn_s_setprio(1);
#pragma unroll
    for (int kk = 0; kk < 2; ++kk)           // kk OUTER: acc reuse 8 instrs apart
#pragma unroll
      for (int ni = 0; ni < 2; ++ni)
#pragma unroll
        for (int mi = 0; mi < 4; ++mi)
          acc[mh * 4 + mi][nh * 2 + ni] = __builtin_amdgcn_mfma_f32_16x16x32_bf16(
              a[mi][kk], bb[bset][ni][kk], acc[mh * 4 + mi][nh * 2 + ni], 0, 0, 0);
    __builtin_amdgcn_s_setprio(0);
  };

  // ---- prologue: buf0 all 4 halves @ k=0; buf1.B halves @ k=64 ----
  STG(pAc, 0,             0,     0);
  STG(pBc, 32768,         0,     0);
  STG(pBc, 49152,         r128K, 0);
  STG(pAc, 16384,         r128K, 0);
  STG(pBc, 65536 + 32768, 0,     64);
  STG(pBc, 65536 + 49152, r128K, 64);
  WAIT_VM4; FENCE; BARRIER;

  const int NT = K >> 6;
  const int NI = NT >> 1;

  for (int tt = 0; tt < ntiles; ++tt) {
    const bool hasn = (tt + 1 < ntiles);
    int m0n = m0, n0n = n0;
    if (hasn) tilecoord(blockIdx.x + (tt + 1) * 256, m0n, n0n);
    const u16* pAn = hasn ? (A + (size_t)(m0n + rowT) * K + colT) : pAc;
    const u16* pBn = hasn ? (Bt + (size_t)(n0n + rowT) * K + colT) : pBc;

    {
      f32x4 z = {0.f, 0.f, 0.f, 0.f};
#pragma unroll
      for (int i = 0; i < 8; ++i)
#pragma unroll
        for (int j = 0; j < 4; ++j) acc[i][j] = z;
    }

    for (int it = 0; it < NI; ++it) {
      const int kP1 = (2 * it + 1) * 64;              // always < K
      const bool last = (it == NI - 1);
      const int kA = last ? 0 : (2 * it + 2) * 64;    // wrap -> next tile k=0
      const int kB = last ? 64 : (2 * it + 3) * 64;   // wrap -> next tile k=64
      const u16* sA = last ? pAn : pAc;
      const u16* sB = last ? pBn : pBc;

      // P1: (mh0,nh0) buf0; stage buf1.A-h0 @ kP1
      rdA(0, 0); rdB(0, 0, 0);
      STG(pAc, 65536, 0, kP1);
      FENCE; BARRIER; WAIT_LGKM0; SB0;
      mfma16(0, 0, 0);
      FENCE; BARRIER;
      // P2: (mh0,nh1); stage buf1.A-h1 @ kP1
      rdB(0, 1, 1);
      STG(pAc, 65536 + 16384, r128K, kP1);
      FENCE; BARRIER; WAIT_LGKM0; SB0;
      mfma16(0, 1, 1);
      FENCE; BARRIER;
      // P3: (mh1,nh1); stage buf0.B-h0 @ kA
      rdA(0, 1);
      STG(sB, 32768, 0, kA);
      FENCE; BARRIER; WAIT_LGKM0; SB0;
      mfma16(1, 1, 1);
      FENCE; BARRIER;
      // P4: (mh1,nh0) regs-only; stage buf0.B-h1 @ kA; vmcnt(4)
      STG(sB, 49152, r128K, kA);
      FENCE; BARRIER; WAIT_LGKM0; SB0;
      mfma16(1, 0, 0);
      WAIT_VM4; FENCE; BARRIER;
      // P5: (mh0,nh0) buf1; stage buf0.A-h0 @ kA
      rdA(1, 0); rdB(1, 0, 0);
      STG(sA, 0, 0, kA);
      FENCE; BARRIER; WAIT_LGKM0; SB0;
      mfma16(0, 0, 0);
      FENCE; BARRIER;
      // P6: (mh0,nh1); stage buf0.A-h1 @ kA
      rdB(1, 1, 1);
      STG(sA, 16384, r128K, kA);
      FENCE; BARRIER; WAIT_LGKM0; SB0;
      mfma16(0, 1, 1);
      FENCE; BARRIER;
      // P7: (mh1,nh1); stage buf1.B-h0 @ kB
      rdA(1, 1);
      STG(sB, 65536 + 32768, 0, kB);
      FENCE; BARRIER; WAIT_LGKM0; SB0;
      mfma16(1, 1, 1);
      FENCE; BARRIER;
      // P8: (mh1,nh0) regs-only; stage buf1.B-h1 @ kB; vmcnt(4)
      STG(sB, 65536 + 49152, r128K, kB);
      FENCE; BARRIER; WAIT_LGKM0; SB0;
      mfma16(1, 0, 0);
      WAIT_VM4; FENCE; BARRIER;
    }

    // ---- epilogue: lane-pair packed stores (even lanes store 2 cols) ----
    // row = r0+r (same for lane pair); cols c0+lr, c0+lr+1 adjacent.
    const bool evenlane = ((lane & 1) == 0);
#pragma unroll
    for (int mi = 0; mi < 8; ++mi)
#pragma unroll
      for (int ni = 0; ni < 4; ++ni) {
        const int r0 = m0 + wm * 128 + (mi >> 2) * 64 + (mi & 3) * 16 + lq * 4;
        const int c = n0 + wn * 64 + (ni >> 1) * 32 + (ni & 1) * 16 + lr;
#pragma unroll
        for (int r = 0; r < 4; ++r) {
          const float v = acc[mi][ni][r];
          const float vp = __shfl_xor(v, 1);
          if (evenlane) {
            if (OUT_BF16) {
              const u32 pk = (u32)f2b(v) | ((u32)f2b(vp) << 16);
              *(u32*)&((u16*)Cv)[(size_t)(r0 + r) * N + c] = pk;
            } else {
              f32x2 pk2; pk2[0] = v; pk2[1] = vp;
              *(f32x2*)&((float*)Cv)[(size_t)(r0 + r) * N + c] = pk2;
            }
          }
        }
      }

    m0 = m0n; n0 = n0n; pAc = pAn; pBc = pBn;
  }
}

// ---------------- segment attention: MFMA + in-register softmax ----------------
__global__ __launch_bounds__(256) void k_attn2(const u16* __restrict__ qkv,
                                               const int* __restrict__ hmap,
                                               u16* __restrict__ att) {
  __shared__ u16 VT[64 * 40];       // V^T[d][k], stride 40 u16, XOR-chunk swizzled
  __shared__ u16 Pl[4][16 * 40];    // per-wave P[16 q][32 k], stride 40 u16

  const int blk = blockIdx.x;
  const int b = blk >> 10, h = (blk >> 6) & 15, s = blk & 63;
  const int t = threadIdx.x, w = t >> 6, lane = t & 63;
  const int lr = lane & 15, lq = lane >> 4;
  const int* hm = hmap + s * 64;
  const size_t bb = (size_t)b * L_SEQ;

  // ---- stage V^T (dilated rows; XOR-chunk swizzle kills write conflicts) ----
  {
    const int kj = t >> 3, d0 = (t & 7) * 8;
    const u16* p = qkv + (bb + hm[2 * kj]) * 3072 + 2048 + h * 64 + d0;
    u16x8 v = *(const u16x8*)p;
#pragma unroll
    for (int j = 0; j < 8; ++j) {
      const int d = d0 + j;
      const int chunk = (kj >> 3) ^ ((d >> 3) & 3);
      VT[d * 40 + chunk * 8 + (kj & 7)] = v[j];
    }
  }

  // ---- Q/K fragment gather: direct global, A/B-frag layouts ----
  const u16* qp = qkv + (bb + hm[16 * w + lr]) * 3072 + h * 64 + lq * 8;
  bf16x8 aq0 = *(const bf16x8*)(qp);
  bf16x8 aq1 = *(const bf16x8*)(qp + 32);
  bf16x8 bk[2][2];
#pragma unroll
  for (int nk = 0; nk < 2; ++nk) {
    const u16* kp = qkv + (bb + hm[2 * (nk * 16 + lr)]) * 3072 + 1024 + h * 64 + lq * 8;
    bk[nk][0] = *(const bf16x8*)(kp);
    bk[nk][1] = *(const bf16x8*)(kp + 32);
  }

  // ---- scores: S[q][kcol], kcol = lr + 16*nk ----
  f32x4 z4 = {0.f, 0.f, 0.f, 0.f};
  f32x4 s0 = __builtin_amdgcn_mfma_f32_16x16x32_bf16(aq0, bk[0][0], z4, 0, 0, 0);
  s0 = __builtin_amdgcn_mfma_f32_16x16x32_bf16(aq1, bk[0][1], s0, 0, 0, 0);
  f32x4 s1 = __builtin_amdgcn_mfma_f32_16x16x32_bf16(aq0, bk[1][0], z4, 0, 0, 0);
  s1 = __builtin_amdgcn_mfma_f32_16x16x32_bf16(aq1, bk[1][1], s1, 0, 0, 0);

  // ---- in-register softmax over 32 kcols (lr-group shuffle reduce) ----
  float inv[4];
  u16* Pw = Pl[w];
#pragma unroll
  for (int r = 0; r < 4; ++r) {
    float a0 = s0[r] * 0.125f, a1 = s1[r] * 0.125f;
    float m = fmaxf(a0, a1);
    m = fmaxf(m, __shfl_xor(m, 1));
    m = fmaxf(m, __shfl_xor(m, 2));
    m = fmaxf(m, __shfl_xor(m, 4));
    m = fmaxf(m, __shfl_xor(m, 8));
    float e0 = __expf(a0 - m), e1 = __expf(a1 - m);
    float sum = e0 + e1;
    sum += __shfl_xor(sum, 1);
    sum += __shfl_xor(sum, 2);
    sum += __shfl_xor(sum, 4);
    sum += __shfl_xor(sum, 8);
    inv[r] = 1.f / sum;
    Pw[(lq * 4 + r) * 40 + lr] = f2b(e0);
    Pw[(lq * 4 + r) * 40 + 16 + lr] = f2b(e1);
  }

  __syncthreads();   // VT visible to all waves; own P writes drained

  // ---- PV: out[q][d] = sum_k P[q][k] * VT[d][k] ----
  bf16x8 ap = *(const bf16x8*)(Pw + lr * 40 + lq * 8);
  f32x4 o[4];
#pragma unroll
  for (int nd = 0; nd < 4; ++nd) {
    const int row = nd * 16 + lr;
    const int chunk = lq ^ ((row >> 3) & 3);
    bf16x8 bv = *(const bf16x8*)(VT + row * 40 + chunk * 8);
    o[nd] = __builtin_amdgcn_mfma_f32_16x16x32_bf16(ap, bv, z4, 0, 0, 0);
  }

  // ---- scatter back to original token order (fuses inverse perm) ----
#pragma unroll
  for (int r = 0; r < 4; ++r) {
    u16* dst = att + (bb + hm[16 * w + lq * 4 + r]) * 1024 + h * 64 + lr;
#pragma unroll
    for (int nd = 0; nd < 4; ++nd)
      dst[nd * 16] = f2b(o[nd][r] * inv[r]);
  }
}

extern "C" void kernel_launch(void* const* d_in, const int* in_sizes, int n_in,
                              void* d_out, int out_size, void* d_ws, size_t ws_size,
                              hipStream_t stream) {
  const float* x = (const float*)d_in[0];
  const float* w_qkv = (const float*)d_in[1];
  const float* w_proj = (const float*)d_in[2];
  const int* hmap = (const int*)d_in[3];
  float* out = (float*)d_out;

  char* ws = (char*)d_ws;
  u16* qkvb  = (u16*)(ws);                   // 16384*3072*2 = 100663296 B
  u16* xb    = (u16*)(ws + 100663296ull);    // 16384*1024*2 = 33554432 B
  u16* wqkvT = (u16*)(ws + 134217728ull);    // 3072*1024*2  = 6291456 B
  u16* wprojT= (u16*)(ws + 140509184ull);    // 1024*1024*2  = 2097152 B -> total 142606336 B
  u16* att = xb;  // xb dead after GEMM1

  k_prep<<<8192, 256, 0, stream>>>(x, xb, w_qkv, wqkvT, w_proj, wprojT);
  // qkv = xb @ w_qkv (bf16 out): 256 persistent blocks x 3 tiles (grid 12x64 tiles)
  k_gemm256p<true><<<256, 512, 0, stream>>>(xb, wqkvT, qkvb, 16384, 3072, 1024, 3, 12);
  k_attn2<<<4096, 256, 0, stream>>>(qkvb, hmap, att);
  // out = att @ w_proj (fp32 out): 256 blocks x 1 tile (grid 4x64 tiles)
  k_gemm256p<false><<<256, 512, 0, stream>>>(att, wprojT, out, 16384, 1024, 1024, 1, 4);
}

// Round 9
// 189.250 us; speedup vs baseline: 1.0677x; 1.0677x over previous
//
#include <hip/hip_runtime.h>

#define L_SEQ 4096

typedef unsigned short u16;
typedef unsigned int u32;
typedef __bf16 bf16_t;
typedef bf16_t bf16x8 __attribute__((ext_vector_type(8)));
typedef float f32x4 __attribute__((ext_vector_type(4)));
typedef unsigned short u16x8 __attribute__((ext_vector_type(8)));
typedef unsigned short u16x4 __attribute__((ext_vector_type(4)));

__device__ __forceinline__ u16 f2b(float f) {
  unsigned u = __float_as_uint(f);
  u += 0x7fffu + ((u >> 16) & 1u);   // RNE
  return (u16)(u >> 16);
}
__device__ __forceinline__ float b2f(u16 b) {
  return __uint_as_float(((unsigned)b) << 16);
}

#define FENCE asm volatile("" ::: "memory")
#define BARRIER __builtin_amdgcn_s_barrier()
#define WAIT_LGKM0 asm volatile("s_waitcnt lgkmcnt(0)" ::: "memory")
#define WAIT_VM4 asm volatile("s_waitcnt vmcnt(4)" ::: "memory")
#define SB0 __builtin_amdgcn_sched_barrier(0)
#define AS1 __attribute__((address_space(1)))
#define AS3 __attribute__((address_space(3)))

// ---------------- fused prep: x->bf16 cvt + both weight transposes ----------------
// blocks [0,4096): cvt 16 elems/thread; [4096,7168): w_qkv^T; [7168,8192): w_proj^T
__global__ __launch_bounds__(256) void k_prep(const float* __restrict__ x,
                                              u16* __restrict__ xb,
                                              const float* __restrict__ wq,
                                              u16* __restrict__ wqT,
                                              const float* __restrict__ wp,
                                              u16* __restrict__ wpT) {
  const int bid = blockIdx.x;
  const int t = threadIdx.x;
  if (bid < 4096) {
    const int i = (bid * 256 + t) * 16;
    f32x4 v0 = *reinterpret_cast<const f32x4*>(x + i);
    f32x4 v1 = *reinterpret_cast<const f32x4*>(x + i + 4);
    f32x4 v2 = *reinterpret_cast<const f32x4*>(x + i + 8);
    f32x4 v3 = *reinterpret_cast<const f32x4*>(x + i + 12);
    u16x8 o0, o1;
#pragma unroll
    for (int j = 0; j < 4; ++j) {
      o0[j] = f2b(v0[j]); o0[4 + j] = f2b(v1[j]);
      o1[j] = f2b(v2[j]); o1[4 + j] = f2b(v3[j]);
    }
    *reinterpret_cast<u16x8*>(xb + i) = o0;
    *reinterpret_cast<u16x8*>(xb + i + 8) = o1;
    return;
  }
  // transpose path: fp32 [R][C] -> bf16 [C][R]
  const float* in; u16* out; int R, C, bx, by;
  if (bid < 7168) {
    const int b2 = bid - 4096;             // 96 x 32 tiles
    in = wq; out = wqT; R = 1024; C = 3072;
    bx = (b2 % 96) * 32; by = (b2 / 96) * 32;
  } else {
    const int b2 = bid - 7168;             // 32 x 32 tiles
    in = wp; out = wpT; R = 1024; C = 1024;
    bx = (b2 % 32) * 32; by = (b2 / 32) * 32;
  }
  __shared__ float tile[32][33];
  const int tx = t & 31, ty = t >> 5;      // (32,8)
#pragma unroll
  for (int i = 0; i < 32; i += 8)
    tile[ty + i][tx] = in[(size_t)(by + ty + i) * C + (bx + tx)];
  __syncthreads();
#pragma unroll
  for (int i = 0; i < 32; i += 8)
    out[(size_t)(bx + ty + i) * R + (by + tx)] = f2b(tile[tx][ty + i]);
}

// ---------------- persistent 256x256 6-phase bf16 GEMM ----------------
// Row-major tile order (round-6 proven). Phases P3+P4 and P7+P8 of the 8-phase
// schedule merged (regs-only MFMA quads share a phase with the preceding one):
// same load issue ORDER, so the counted-vmcnt drain invariant is unchanged.
template <bool OUT_BF16>
__global__ __launch_bounds__(512, 2) void k_gemm256p(const u16* __restrict__ A,
                                                     const u16* __restrict__ Bt,
                                                     void* __restrict__ Cv,
                                                     int M, int N, int K,
                                                     int ntiles, int gx) {
  __shared__ __align__(16) char lds[131072];
  const int tid = threadIdx.x;
  const int wid = tid >> 6, lane = tid & 63;
  const int wm = wid >> 2, wn = wid & 3;      // 2x4 wave grid
  const int lr = lane & 15, lq = lane >> 4;
  const int xr = (lr & 7) << 4;               // read-side XOR swizzle
  const int koff0 = (lq * 16) ^ xr;
  const int koff1 = (64 | (lq * 16)) ^ xr;

  const int cpx = 32 * ntiles;                // (256*ntiles)/8
  auto tilecoord = [&](int ff, int& mm, int& nn) {
    int swz = (ff & 7) * cpx + (ff >> 3);
    mm = (swz / gx) * 256; nn = (swz % gx) * 256;
  };

  // per-thread staging constants (source pre-swizzled to match swizzled reads)
  const int rowT = tid >> 3;                                        // 0..63
  const int colT = (((tid * 16) & 127) ^ ((rowT & 7) << 4)) >> 1;   // u16 units
  const size_t r64K = (size_t)64 * K;
  const size_t r128K = (size_t)128 * K;

  int m0, n0;
  tilecoord(blockIdx.x, m0, n0);
  const u16* pAc = A + (size_t)(m0 + rowT) * K + colT;
  const u16* pBc = Bt + (size_t)(n0 + rowT) * K + colT;

  f32x4 acc[8][4];
  bf16x8 a[4][2];
  bf16x8 bb[2][2][2];

  auto STG = [&](const u16* bp, int region, size_t hoff, int k0) {
    const u16* s0 = bp + hoff + k0;
    __builtin_amdgcn_global_load_lds((const AS1 void*)s0,
                                     (AS3 void*)(lds + region + wid * 1024), 16, 0, 0);
    __builtin_amdgcn_global_load_lds((const AS1 void*)(s0 + r64K),
                                     (AS3 void*)(lds + region + 8192 + wid * 1024), 16, 0, 0);
  };
  auto rdA = [&](int dbuf, int mh) {
#pragma unroll
    for (int mi = 0; mi < 4; ++mi) {
      const int base = dbuf * 65536 + wm * 16384 + (mh * 64 + mi * 16 + lr) * 128;
      a[mi][0] = *(const bf16x8*)(lds + base + koff0);
      a[mi][1] = *(const bf16x8*)(lds + base + koff1);
    }
  };
  auto rdB = [&](int dbuf, int nh, int bset) {
#pragma unroll
    for (int ni = 0; ni < 2; ++ni) {
      const int base = dbuf * 65536 + 32768 + (wn >> 1) * 16384 +
                       ((wn & 1) * 64 + nh * 32 + ni * 16 + lr) * 128;
      bb[bset][ni][0] = *(const bf16x8*)(lds + base + koff0);
      bb[bset][ni][1] = *(const bf16x8*)(lds + base + koff1);
    }
  };
  auto mfma16 = [&](int mh, int nh, int bset) {
    __builtin_amdgcn_s_setprio(1);
#pragma unroll
    for (int kk = 0; kk < 2; ++kk)           // kk OUTER: acc reuse 8 instrs apart
#pragma unroll
      for (int ni = 0; ni < 2; ++ni)
#pragma unroll
        for (int mi = 0; mi < 4; ++mi)
          acc[mh * 4 + mi][nh * 2 + ni] = __builtin_amdgcn_mfma_f32_16x16x32_bf16(
              a[mi][kk], bb[bset][ni][kk], acc[mh * 4 + mi][nh * 2 + ni], 0, 0, 0);
    __builtin_amdgcn_s_setprio(0);
  };

  // ---- prologue: buf0 all 4 halves @ k=0; buf1.B halves @ k=64 ----
  STG(pAc, 0,             0,     0);
  STG(pBc, 32768,         0,     0);
  STG(pBc, 49152,         r128K, 0);
  STG(pAc, 16384,         r128K, 0);
  STG(pBc, 65536 + 32768, 0,     64);
  STG(pBc, 65536 + 49152, r128K, 64);
  WAIT_VM4; FENCE; BARRIER;   // drain buf0 (8 oldest); buf1.B (4) stays in flight

  const int NT = K >> 6;
  const int NI = NT >> 1;

  for (int tt = 0; tt < ntiles; ++tt) {
    const bool hasn = (tt + 1 < ntiles);
    int m0n = m0, n0n = n0;
    if (hasn) tilecoord(blockIdx.x + (tt + 1) * 256, m0n, n0n);
    const u16* pAn = hasn ? (A + (size_t)(m0n + rowT) * K + colT) : pAc;
    const u16* pBn = hasn ? (Bt + (size_t)(n0n + rowT) * K + colT) : pBc;

    {
      f32x4 z = {0.f, 0.f, 0.f, 0.f};
#pragma unroll
      for (int i = 0; i < 8; ++i)
#pragma unroll
        for (int j = 0; j < 4; ++j) acc[i][j] = z;
    }

    for (int it = 0; it < NI; ++it) {
      const int kP1 = (2 * it + 1) * 64;              // always < K
      const bool last = (it == NI - 1);
      const int kA = last ? 0 : (2 * it + 2) * 64;    // wrap -> next tile k=0
      const int kB = last ? 64 : (2 * it + 3) * 64;   // wrap -> next tile k=64
      const u16* sA = last ? pAn : pAc;
      const u16* sB = last ? pBn : pBc;

      // P1: (mh0,nh0) buf0; stage buf1.A-h0 @ kP1
      rdA(0, 0); rdB(0, 0, 0);
      STG(pAc, 65536, 0, kP1);
      FENCE; BARRIER; WAIT_LGKM0; SB0;
      mfma16(0, 0, 0);
      FENCE; BARRIER;
      // P2: (mh0,nh1); stage buf1.A-h1 @ kP1
      rdB(0, 1, 1);
      STG(pAc, 65536 + 16384, r128K, kP1);
      FENCE; BARRIER; WAIT_LGKM0; SB0;
      mfma16(0, 1, 1);
      FENCE; BARRIER;
      // P3' (merged P3+P4): (mh1,nh1)+(mh1,nh0); stage buf0.B h0+h1 @ kA; vmcnt(4)
      rdA(0, 1);
      STG(sB, 32768, 0, kA);
      STG(sB, 49152, r128K, kA);
      FENCE; BARRIER; WAIT_LGKM0; SB0;
      mfma16(1, 1, 1);
      mfma16(1, 0, 0);
      WAIT_VM4; FENCE; BARRIER;   // drains {prev buf1.B, buf1.A}; leaves buf0.B(4)
      // P4' (old P5): (mh0,nh0) buf1; stage buf0.A-h0 @ kA
      rdA(1, 0); rdB(1, 0, 0);
      STG(sA, 0, 0, kA);
      FENCE; BARRIER; WAIT_LGKM0; SB0;
      mfma16(0, 0, 0);
      FENCE; BARRIER;
      // P5' (old P6): (mh0,nh1); stage buf0.A-h1 @ kA
      rdB(1, 1, 1);
      STG(sA, 16384, r128K, kA);
      FENCE; BARRIER; WAIT_LGKM0; SB0;
      mfma16(0, 1, 1);
      FENCE; BARRIER;
      // P6' (merged P7+P8): (mh1,nh1)+(mh1,nh0); stage buf1.B h0+h1 @ kB; vmcnt(4)
      rdA(1, 1);
      STG(sB, 65536 + 32768, 0, kB);
      STG(sB, 65536 + 49152, r128K, kB);
      FENCE; BARRIER; WAIT_LGKM0; SB0;
      mfma16(1, 1, 1);
      mfma16(1, 0, 0);
      WAIT_VM4; FENCE; BARRIER;   // drains {buf0.B, buf0.A}; leaves buf1.B(4)
    }

    // ---- epilogue (scalar stores, round-6 proven); overlaps next tile P1-P3 ----
#pragma unroll
    for (int mi = 0; mi < 8; ++mi)
#pragma unroll
      for (int ni = 0; ni < 4; ++ni) {
        const int r0 = m0 + wm * 128 + (mi >> 2) * 64 + (mi & 3) * 16 + lq * 4;
        const int c = n0 + wn * 64 + (ni >> 1) * 32 + (ni & 1) * 16 + lr;
#pragma unroll
        for (int r = 0; r < 4; ++r) {
          const float v = acc[mi][ni][r];
          if (OUT_BF16)
            ((u16*)Cv)[(size_t)(r0 + r) * N + c] = f2b(v);
          else
            ((float*)Cv)[(size_t)(r0 + r) * N + c] = v;
        }
      }

    m0 = m0n; n0 = n0n; pAc = pAn; pBc = pBn;
  }
}

// ---------------- segment attention: MFMA + in-register softmax ----------------
__global__ __launch_bounds__(256) void k_attn2(const u16* __restrict__ qkv,
                                               const int* __restrict__ hmap,
                                               u16* __restrict__ att) {
  __shared__ u16 VT[64 * 40];       // V^T[d][k], stride 40 u16, XOR-chunk swizzled
  __shared__ u16 Pl[4][16 * 40];    // per-wave P[16 q][32 k], stride 40 u16

  const int blk = blockIdx.x;
  const int b = blk >> 10, h = (blk >> 6) & 15, s = blk & 63;
  const int t = threadIdx.x, w = t >> 6, lane = t & 63;
  const int lr = lane & 15, lq = lane >> 4;
  const int* hm = hmap + s * 64;
  const size_t bb = (size_t)b * L_SEQ;

  // ---- stage V^T (dilated rows; XOR-chunk swizzle kills write conflicts) ----
  {
    const int kj = t >> 3, d0 = (t & 7) * 8;
    const u16* p = qkv + (bb + hm[2 * kj]) * 3072 + 2048 + h * 64 + d0;
    u16x8 v = *(const u16x8*)p;
#pragma unroll
    for (int j = 0; j < 8; ++j) {
      const int d = d0 + j;
      const int chunk = (kj >> 3) ^ ((d >> 3) & 3);
      VT[d * 40 + chunk * 8 + (kj & 7)] = v[j];
    }
  }

  // ---- Q/K fragment gather: direct global, A/B-frag layouts ----
  const u16* qp = qkv + (bb + hm[16 * w + lr]) * 3072 + h * 64 + lq * 8;
  bf16x8 aq0 = *(const bf16x8*)(qp);
  bf16x8 aq1 = *(const bf16x8*)(qp + 32);
  bf16x8 bk[2][2];
#pragma unroll
  for (int nk = 0; nk < 2; ++nk) {
    const u16* kp = qkv + (bb + hm[2 * (nk * 16 + lr)]) * 3072 + 1024 + h * 64 + lq * 8;
    bk[nk][0] = *(const bf16x8*)(kp);
    bk[nk][1] = *(const bf16x8*)(kp + 32);
  }

  // ---- scores: S[q][kcol], kcol = lr + 16*nk ----
  f32x4 z4 = {0.f, 0.f, 0.f, 0.f};
  f32x4 s0 = __builtin_amdgcn_mfma_f32_16x16x32_bf16(aq0, bk[0][0], z4, 0, 0, 0);
  s0 = __builtin_amdgcn_mfma_f32_16x16x32_bf16(aq1, bk[0][1], s0, 0, 0, 0);
  f32x4 s1 = __builtin_amdgcn_mfma_f32_16x16x32_bf16(aq0, bk[1][0], z4, 0, 0, 0);
  s1 = __builtin_amdgcn_mfma_f32_16x16x32_bf16(aq1, bk[1][1], s1, 0, 0, 0);

  // ---- in-register softmax over 32 kcols (lr-group shuffle reduce) ----
  float inv[4];
  u16* Pw = Pl[w];
#pragma unroll
  for (int r = 0; r < 4; ++r) {
    float a0 = s0[r] * 0.125f, a1 = s1[r] * 0.125f;
    float m = fmaxf(a0, a1);
    m = fmaxf(m, __shfl_xor(m, 1));
    m = fmaxf(m, __shfl_xor(m, 2));
    m = fmaxf(m, __shfl_xor(m, 4));
    m = fmaxf(m, __shfl_xor(m, 8));
    float e0 = __expf(a0 - m), e1 = __expf(a1 - m);
    float sum = e0 + e1;
    sum += __shfl_xor(sum, 1);
    sum += __shfl_xor(sum, 2);
    sum += __shfl_xor(sum, 4);
    sum += __shfl_xor(sum, 8);
    inv[r] = 1.f / sum;
    Pw[(lq * 4 + r) * 40 + lr] = f2b(e0);
    Pw[(lq * 4 + r) * 40 + 16 + lr] = f2b(e1);
  }

  __syncthreads();   // VT visible to all waves; own P writes drained

  // ---- PV: out[q][d] = sum_k P[q][k] * VT[d][k] ----
  bf16x8 ap = *(const bf16x8*)(Pw + lr * 40 + lq * 8);
  f32x4 o[4];
#pragma unroll
  for (int nd = 0; nd < 4; ++nd) {
    const int row = nd * 16 + lr;
    const int chunk = lq ^ ((row >> 3) & 3);
    bf16x8 bv = *(const bf16x8*)(VT + row * 40 + chunk * 8);
    o[nd] = __builtin_amdgcn_mfma_f32_16x16x32_bf16(ap, bv, z4, 0, 0, 0);
  }

  // ---- scatter back to original token order (fuses inverse perm) ----
#pragma unroll
  for (int r = 0; r < 4; ++r) {
    u16* dst = att + (bb + hm[16 * w + lq * 4 + r]) * 1024 + h * 64 + lr;
#pragma unroll
    for (int nd = 0; nd < 4; ++nd)
      dst[nd * 16] = f2b(o[nd][r] * inv[r]);
  }
}

extern "C" void kernel_launch(void* const* d_in, const int* in_sizes, int n_in,
                              void* d_out, int out_size, void* d_ws, size_t ws_size,
                              hipStream_t stream) {
  const float* x = (const float*)d_in[0];
  const float* w_qkv = (const float*)d_in[1];
  const float* w_proj = (const float*)d_in[2];
  const int* hmap = (const int*)d_in[3];
  float* out = (float*)d_out;

  char* ws = (char*)d_ws;
  u16* qkvb  = (u16*)(ws);                   // 16384*3072*2 = 100663296 B
  u16* xb    = (u16*)(ws + 100663296ull);    // 16384*1024*2 = 33554432 B
  u16* wqkvT = (u16*)(ws + 134217728ull);    // 3072*1024*2  = 6291456 B
  u16* wprojT= (u16*)(ws + 140509184ull);    // 1024*1024*2  = 2097152 B -> total 142606336 B
  u16* att = xb;  // xb dead after GEMM1

  k_prep<<<8192, 256, 0, stream>>>(x, xb, w_qkv, wqkvT, w_proj, wprojT);
  // qkv = xb @ w_qkv (bf16 out): 256 persistent blocks x 3 tiles (grid 12x64 tiles)
  k_gemm256p<true><<<256, 512, 0, stream>>>(xb, wqkvT, qkvb, 16384, 3072, 1024, 3, 12);
  k_attn2<<<4096, 256, 0, stream>>>(qkvb, hmap, att);
  // out = att @ w_proj (fp32 out): 256 blocks x 1 tile (grid 4x64 tiles)
  k_gemm256p<false><<<256, 512, 0, stream>>>(att, wprojT, out, 16384, 1024, 1024, 1, 4);
}

// Round 10
// 166.450 us; speedup vs baseline: 1.2139x; 1.1370x over previous
//
#include <hip/hip_runtime.h>

#define L_SEQ 4096

typedef unsigned short u16;
typedef unsigned int u32;
typedef __bf16 bf16_t;
typedef bf16_t bf16x8 __attribute__((ext_vector_type(8)));
typedef float f32x4 __attribute__((ext_vector_type(4)));
typedef unsigned short u16x8 __attribute__((ext_vector_type(8)));

__device__ __forceinline__ u16 f2b(float f) {
  unsigned u = __float_as_uint(f);
  u += 0x7fffu + ((u >> 16) & 1u);   // RNE
  return (u16)(u >> 16);
}
__device__ __forceinline__ float b2f(u16 b) {
  return __uint_as_float(((unsigned)b) << 16);
}

#define FENCE asm volatile("" ::: "memory")
#define BARRIER __builtin_amdgcn_s_barrier()
#define WAIT_LGKM0 asm volatile("s_waitcnt lgkmcnt(0)" ::: "memory")
#define WAIT_VM4 asm volatile("s_waitcnt vmcnt(4)" ::: "memory")
#define SB0 __builtin_amdgcn_sched_barrier(0)
#define AS1 __attribute__((address_space(1)))
#define AS3 __attribute__((address_space(3)))

// ---------------- fused prep ----------------
// [0,4096): x->bf16 cvt (16 elems/thread)
// [4096,7168): w_qkv^T   [7168,8192): w_proj^T
// [8192,9216): xg = bf16(x gathered in dilated-Hilbert order), 8 rows/block
__global__ __launch_bounds__(256) void k_prep(const float* __restrict__ x,
                                              u16* __restrict__ xb,
                                              const float* __restrict__ wq,
                                              u16* __restrict__ wqT,
                                              const float* __restrict__ wp,
                                              u16* __restrict__ wpT,
                                              const int* __restrict__ hmap,
                                              u16* __restrict__ xg) {
  const int bid = blockIdx.x;
  const int t = threadIdx.x;
  if (bid < 4096) {
    const int i = (bid * 256 + t) * 16;
    f32x4 v0 = *reinterpret_cast<const f32x4*>(x + i);
    f32x4 v1 = *reinterpret_cast<const f32x4*>(x + i + 4);
    f32x4 v2 = *reinterpret_cast<const f32x4*>(x + i + 8);
    f32x4 v3 = *reinterpret_cast<const f32x4*>(x + i + 12);
    u16x8 o0, o1;
#pragma unroll
    for (int j = 0; j < 4; ++j) {
      o0[j] = f2b(v0[j]); o0[4 + j] = f2b(v1[j]);
      o1[j] = f2b(v2[j]); o1[4 + j] = f2b(v3[j]);
    }
    *reinterpret_cast<u16x8*>(xb + i) = o0;
    *reinterpret_cast<u16x8*>(xb + i + 8) = o1;
    return;
  }
  if (bid >= 8192) {   // xg gather (reads fp32 x directly -> no race with xb)
    const int g = bid - 8192;
    const int gi = g * 8 + (t >> 5);          // xg row, 0..8191
    const int lane32 = t & 31;
    const int b = gi >> 11, i = gi & 2047;
    const int s = i >> 5, j = i & 31;
    const int token = hmap[s * 64 + 2 * j];
    const float* src = x + ((size_t)(b * 4096 + token)) * 1024 + lane32 * 32;
    u16* dst = xg + (size_t)gi * 1024 + lane32 * 32;
#pragma unroll
    for (int c = 0; c < 4; ++c) {
      f32x4 v0 = *(const f32x4*)(src + c * 8);
      f32x4 v1 = *(const f32x4*)(src + c * 8 + 4);
      u16x8 o;
#pragma unroll
      for (int q = 0; q < 4; ++q) { o[q] = f2b(v0[q]); o[4 + q] = f2b(v1[q]); }
      *(u16x8*)(dst + c * 8) = o;
    }
    return;
  }
  // transpose path: fp32 [R][C] -> bf16 [C][R]
  const float* in; u16* out; int R, C, bx, by;
  if (bid < 7168) {
    const int b2 = bid - 4096;             // 96 x 32 tiles
    in = wq; out = wqT; R = 1024; C = 3072;
    bx = (b2 % 96) * 32; by = (b2 / 96) * 32;
  } else {
    const int b2 = bid - 7168;             // 32 x 32 tiles
    in = wp; out = wpT; R = 1024; C = 1024;
    bx = (b2 % 32) * 32; by = (b2 / 32) * 32;
  }
  __shared__ float tile[32][33];
  const int tx = t & 31, ty = t >> 5;      // (32,8)
#pragma unroll
  for (int i = 0; i < 32; i += 8)
    tile[ty + i][tx] = in[(size_t)(by + ty + i) * C + (bx + tx)];
  __syncthreads();
#pragma unroll
  for (int i = 0; i < 32; i += 8)
    out[(size_t)(bx + ty + i) * R + (by + tx)] = f2b(tile[tx][ty + i]);
}

// ---------------- 256x256 6-phase bf16 GEMM body (round-9 proven) ----------------
template <bool OUT_BF16>
__device__ __forceinline__ void gemm_body(char* lds, const u16* __restrict__ A,
                                          const u16* __restrict__ Bt,
                                          void* __restrict__ Cv,
                                          int N, int K, int ntiles, int gx, int bid) {
  const int tid = threadIdx.x;
  const int wid = tid >> 6, lane = tid & 63;
  const int wm = wid >> 2, wn = wid & 3;      // 2x4 wave grid
  const int lr = lane & 15, lq = lane >> 4;
  const int xr = (lr & 7) << 4;               // read-side XOR swizzle
  const int koff0 = (lq * 16) ^ xr;
  const int koff1 = (64 | (lq * 16)) ^ xr;

  const int cpx = 32 * ntiles;
  auto tilecoord = [&](int ff, int& mm, int& nn) {
    int swz = (ff & 7) * cpx + (ff >> 3);
    mm = (swz / gx) * 256; nn = (swz % gx) * 256;
  };

  const int rowT = tid >> 3;                                        // 0..63
  const int colT = (((tid * 16) & 127) ^ ((rowT & 7) << 4)) >> 1;   // u16 units
  const size_t r64K = (size_t)64 * K;
  const size_t r128K = (size_t)128 * K;

  int m0, n0;
  tilecoord(bid, m0, n0);
  const u16* pAc = A + (size_t)(m0 + rowT) * K + colT;
  const u16* pBc = Bt + (size_t)(n0 + rowT) * K + colT;

  f32x4 acc[8][4];
  bf16x8 a[4][2];
  bf16x8 bb[2][2][2];

  auto STG = [&](const u16* bp, int region, size_t hoff, int k0) {
    const u16* s0 = bp + hoff + k0;
    __builtin_amdgcn_global_load_lds((const AS1 void*)s0,
                                     (AS3 void*)(lds + region + wid * 1024), 16, 0, 0);
    __builtin_amdgcn_global_load_lds((const AS1 void*)(s0 + r64K),
                                     (AS3 void*)(lds + region + 8192 + wid * 1024), 16, 0, 0);
  };
  auto rdA = [&](int dbuf, int mh) {
#pragma unroll
    for (int mi = 0; mi < 4; ++mi) {
      const int base = dbuf * 65536 + wm * 16384 + (mh * 64 + mi * 16 + lr) * 128;
      a[mi][0] = *(const bf16x8*)(lds + base + koff0);
      a[mi][1] = *(const bf16x8*)(lds + base + koff1);
    }
  };
  auto rdB = [&](int dbuf, int nh, int bset) {
#pragma unroll
    for (int ni = 0; ni < 2; ++ni) {
      const int base = dbuf * 65536 + 32768 + (wn >> 1) * 16384 +
                       ((wn & 1) * 64 + nh * 32 + ni * 16 + lr) * 128;
      bb[bset][ni][0] = *(const bf16x8*)(lds + base + koff0);
      bb[bset][ni][1] = *(const bf16x8*)(lds + base + koff1);
    }
  };
  auto mfma16 = [&](int mh, int nh, int bset) {
    __builtin_amdgcn_s_setprio(1);
#pragma unroll
    for (int kk = 0; kk < 2; ++kk)
#pragma unroll
      for (int ni = 0; ni < 2; ++ni)
#pragma unroll
        for (int mi = 0; mi < 4; ++mi)
          acc[mh * 4 + mi][nh * 2 + ni] = __builtin_amdgcn_mfma_f32_16x16x32_bf16(
              a[mi][kk], bb[bset][ni][kk], acc[mh * 4 + mi][nh * 2 + ni], 0, 0, 0);
    __builtin_amdgcn_s_setprio(0);
  };

  STG(pAc, 0,             0,     0);
  STG(pBc, 32768,         0,     0);
  STG(pBc, 49152,         r128K, 0);
  STG(pAc, 16384,         r128K, 0);
  STG(pBc, 65536 + 32768, 0,     64);
  STG(pBc, 65536 + 49152, r128K, 64);
  WAIT_VM4; FENCE; BARRIER;

  const int NT = K >> 6;
  const int NI = NT >> 1;

  for (int tt = 0; tt < ntiles; ++tt) {
    const bool hasn = (tt + 1 < ntiles);
    int m0n = m0, n0n = n0;
    if (hasn) tilecoord(bid + (tt + 1) * 256, m0n, n0n);
    const u16* pAn = hasn ? (A + (size_t)(m0n + rowT) * K + colT) : pAc;
    const u16* pBn = hasn ? (Bt + (size_t)(n0n + rowT) * K + colT) : pBc;

    {
      f32x4 z = {0.f, 0.f, 0.f, 0.f};
#pragma unroll
      for (int i = 0; i < 8; ++i)
#pragma unroll
        for (int j = 0; j < 4; ++j) acc[i][j] = z;
    }

    for (int it = 0; it < NI; ++it) {
      const int kP1 = (2 * it + 1) * 64;
      const bool last = (it == NI - 1);
      const int kA = last ? 0 : (2 * it + 2) * 64;
      const int kB = last ? 64 : (2 * it + 3) * 64;
      const u16* sA = last ? pAn : pAc;
      const u16* sB = last ? pBn : pBc;

      // P1
      rdA(0, 0); rdB(0, 0, 0);
      STG(pAc, 65536, 0, kP1);
      FENCE; BARRIER; WAIT_LGKM0; SB0;
      mfma16(0, 0, 0);
      FENCE; BARRIER;
      // P2
      rdB(0, 1, 1);
      STG(pAc, 65536 + 16384, r128K, kP1);
      FENCE; BARRIER; WAIT_LGKM0; SB0;
      mfma16(0, 1, 1);
      FENCE; BARRIER;
      // P3' (merged)
      rdA(0, 1);
      STG(sB, 32768, 0, kA);
      STG(sB, 49152, r128K, kA);
      FENCE; BARRIER; WAIT_LGKM0; SB0;
      mfma16(1, 1, 1);
      mfma16(1, 0, 0);
      WAIT_VM4; FENCE; BARRIER;
      // P4'
      rdA(1, 0); rdB(1, 0, 0);
      STG(sA, 0, 0, kA);
      FENCE; BARRIER; WAIT_LGKM0; SB0;
      mfma16(0, 0, 0);
      FENCE; BARRIER;
      // P5'
      rdB(1, 1, 1);
      STG(sA, 16384, r128K, kA);
      FENCE; BARRIER; WAIT_LGKM0; SB0;
      mfma16(0, 1, 1);
      FENCE; BARRIER;
      // P6' (merged)
      rdA(1, 1);
      STG(sB, 65536 + 32768, 0, kB);
      STG(sB, 65536 + 49152, r128K, kB);
      FENCE; BARRIER; WAIT_LGKM0; SB0;
      mfma16(1, 1, 1);
      mfma16(1, 0, 0);
      WAIT_VM4; FENCE; BARRIER;
    }

#pragma unroll
    for (int mi = 0; mi < 8; ++mi)
#pragma unroll
      for (int ni = 0; ni < 4; ++ni) {
        const int r0 = m0 + wm * 128 + (mi >> 2) * 64 + (mi & 3) * 16 + lq * 4;
        const int c = n0 + wn * 64 + (ni >> 1) * 32 + (ni & 1) * 16 + lr;
#pragma unroll
        for (int r = 0; r < 4; ++r) {
          const float v = acc[mi][ni][r];
          if (OUT_BF16)
            ((u16*)Cv)[(size_t)(r0 + r) * N + c] = f2b(v);
          else
            ((float*)Cv)[(size_t)(r0 + r) * N + c] = v;
        }
      }

    m0 = m0n; n0 = n0n; pAc = pAn; pBc = pBn;
  }
}

// Q-GEMM (blocks 0-255) + KV-GEMM (blocks 256-511) in one dispatch.
__global__ __launch_bounds__(512, 2) void k_gemm_qkv(const u16* __restrict__ xb,
                                                     const u16* __restrict__ xg,
                                                     const u16* __restrict__ wT,
                                                     u16* __restrict__ qb,
                                                     u16* __restrict__ kvb) {
  __shared__ __align__(16) char lds[131072];
  const bool kv = (blockIdx.x >= 256);
  gemm_body<true>(lds,
                  kv ? xg : xb,
                  kv ? (wT + 1024 * 1024) : wT,
                  kv ? (void*)kvb : (void*)qb,
                  kv ? 2048 : 1024, 1024, 1, kv ? 8 : 4,
                  blockIdx.x & 255);
}

__global__ __launch_bounds__(512, 2) void k_gemm_proj(const u16* __restrict__ A,
                                                      const u16* __restrict__ Bt,
                                                      float* __restrict__ C) {
  __shared__ __align__(16) char lds[131072];
  gemm_body<false>(lds, A, Bt, C, 1024, 1024, 1, 4, blockIdx.x);
}

// ---------------- segment attention: MFMA + in-register softmax ----------------
// Q gathered from qb (stride 1024); K/V dense from kvb (stride 2048, seg order).
__global__ __launch_bounds__(256) void k_attn2(const u16* __restrict__ qb,
                                               const u16* __restrict__ kvb,
                                               const int* __restrict__ hmap,
                                               u16* __restrict__ att) {
  __shared__ u16 VT[64 * 40];       // V^T[d][k], stride 40 u16, XOR-chunk swizzled
  __shared__ u16 Pl[4][16 * 40];    // per-wave P[16 q][32 k], stride 40 u16

  const int blk = blockIdx.x;
  const int b = blk >> 10, h = (blk >> 6) & 15, s = blk & 63;
  const int t = threadIdx.x, w = t >> 6, lane = t & 63;
  const int lr = lane & 15, lq = lane >> 4;
  const int* hm = hmap + s * 64;
  const size_t bb4 = (size_t)b * L_SEQ;
  const size_t kvrow0 = (size_t)(b * 2048 + s * 32);

  // ---- stage V^T (dense rows; XOR-chunk swizzle kills write conflicts) ----
  {
    const int kj = t >> 3, d0 = (t & 7) * 8;
    const u16* p = kvb + (kvrow0 + kj) * 2048 + 1024 + h * 64 + d0;
    u16x8 v = *(const u16x8*)p;
#pragma unroll
    for (int j = 0; j < 8; ++j) {
      const int d = d0 + j;
      const int chunk = (kj >> 3) ^ ((d >> 3) & 3);
      VT[d * 40 + chunk * 8 + (kj & 7)] = v[j];
    }
  }

  // ---- Q (gathered) / K (dense) fragments ----
  const u16* qp = qb + (bb4 + hm[16 * w + lr]) * 1024 + h * 64 + lq * 8;
  bf16x8 aq0 = *(const bf16x8*)(qp);
  bf16x8 aq1 = *(const bf16x8*)(qp + 32);
  bf16x8 bk[2][2];
#pragma unroll
  for (int nk = 0; nk < 2; ++nk) {
    const u16* kp = kvb + (kvrow0 + nk * 16 + lr) * 2048 + h * 64 + lq * 8;
    bk[nk][0] = *(const bf16x8*)(kp);
    bk[nk][1] = *(const bf16x8*)(kp + 32);
  }

  // ---- scores ----
  f32x4 z4 = {0.f, 0.f, 0.f, 0.f};
  f32x4 s0 = __builtin_amdgcn_mfma_f32_16x16x32_bf16(aq0, bk[0][0], z4, 0, 0, 0);
  s0 = __builtin_amdgcn_mfma_f32_16x16x32_bf16(aq1, bk[0][1], s0, 0, 0, 0);
  f32x4 s1 = __builtin_amdgcn_mfma_f32_16x16x32_bf16(aq0, bk[1][0], z4, 0, 0, 0);
  s1 = __builtin_amdgcn_mfma_f32_16x16x32_bf16(aq1, bk[1][1], s1, 0, 0, 0);

  // ---- in-register softmax (lr-group shuffle reduce) ----
  float inv[4];
  u16* Pw = Pl[w];
#pragma unroll
  for (int r = 0; r < 4; ++r) {
    float a0 = s0[r] * 0.125f, a1 = s1[r] * 0.125f;
    float m = fmaxf(a0, a1);
    m = fmaxf(m, __shfl_xor(m, 1));
    m = fmaxf(m, __shfl_xor(m, 2));
    m = fmaxf(m, __shfl_xor(m, 4));
    m = fmaxf(m, __shfl_xor(m, 8));
    float e0 = __expf(a0 - m), e1 = __expf(a1 - m);
    float sum = e0 + e1;
    sum += __shfl_xor(sum, 1);
    sum += __shfl_xor(sum, 2);
    sum += __shfl_xor(sum, 4);
    sum += __shfl_xor(sum, 8);
    inv[r] = 1.f / sum;
    Pw[(lq * 4 + r) * 40 + lr] = f2b(e0);
    Pw[(lq * 4 + r) * 40 + 16 + lr] = f2b(e1);
  }

  __syncthreads();

  // ---- PV ----
  bf16x8 ap = *(const bf16x8*)(Pw + lr * 40 + lq * 8);
  f32x4 o[4];
#pragma unroll
  for (int nd = 0; nd < 4; ++nd) {
    const int row = nd * 16 + lr;
    const int chunk = lq ^ ((row >> 3) & 3);
    bf16x8 bv = *(const bf16x8*)(VT + row * 40 + chunk * 8);
    o[nd] = __builtin_amdgcn_mfma_f32_16x16x32_bf16(ap, bv, z4, 0, 0, 0);
  }

  // ---- scatter back to original token order ----
#pragma unroll
  for (int r = 0; r < 4; ++r) {
    u16* dst = att + (bb4 + hm[16 * w + lq * 4 + r]) * 1024 + h * 64 + lr;
#pragma unroll
    for (int nd = 0; nd < 4; ++nd)
      dst[nd * 16] = f2b(o[nd][r] * inv[r]);
  }
}

extern "C" void kernel_launch(void* const* d_in, const int* in_sizes, int n_in,
                              void* d_out, int out_size, void* d_ws, size_t ws_size,
                              hipStream_t stream) {
  const float* x = (const float*)d_in[0];
  const float* w_qkv = (const float*)d_in[1];
  const float* w_proj = (const float*)d_in[2];
  const int* hmap = (const int*)d_in[3];
  float* out = (float*)d_out;

  char* ws = (char*)d_ws;
  u16* qb    = (u16*)(ws);                   // 16384*1024*2 = 33554432
  u16* kvb   = (u16*)(ws + 33554432ull);     //  8192*2048*2 = 33554432
  u16* xb    = (u16*)(ws + 67108864ull);     // 16384*1024*2 = 33554432 (att aliases)
  u16* xg    = (u16*)(ws + 100663296ull);    //  8192*1024*2 = 16777216
  u16* wqkvT = (u16*)(ws + 117440512ull);    //  3072*1024*2 = 6291456
  u16* wpT   = (u16*)(ws + 123731968ull);    //  1024*1024*2 = 2097152  -> 125829120 total
  u16* att = xb;  // xb dead after Q-GEMM

  k_prep<<<9216, 256, 0, stream>>>(x, xb, w_qkv, wqkvT, w_proj, wpT, hmap, xg);
  // Q-GEMM (256 blocks) + KV-GEMM (256 blocks), one dispatch
  k_gemm_qkv<<<512, 512, 0, stream>>>(xb, xg, wqkvT, qb, kvb);
  k_attn2<<<4096, 256, 0, stream>>>(qb, kvb, hmap, att);
  // out = att @ w_proj (fp32 out)
  k_gemm_proj<<<256, 512, 0, stream>>>(att, wpT, out);
}

// Round 11
// 154.044 us; speedup vs baseline: 1.3117x; 1.0805x over previous
//
#include <hip/hip_runtime.h>

#define L_SEQ 4096

typedef unsigned short u16;
typedef unsigned int u32;
typedef __bf16 bf16_t;
typedef bf16_t bf16x8 __attribute__((ext_vector_type(8)));
typedef float f32x4 __attribute__((ext_vector_type(4)));
typedef unsigned short u16x8 __attribute__((ext_vector_type(8)));

__device__ __forceinline__ u16 f2b(float f) {
  unsigned u = __float_as_uint(f);
  u += 0x7fffu + ((u >> 16) & 1u);   // RNE
  return (u16)(u >> 16);
}
__device__ __forceinline__ float b2f(u16 b) {
  return __uint_as_float(((unsigned)b) << 16);
}

#define FENCE asm volatile("" ::: "memory")
#define BARRIER __builtin_amdgcn_s_barrier()
#define WAIT_LGKM0 asm volatile("s_waitcnt lgkmcnt(0)" ::: "memory")
#define WAIT_VM4 asm volatile("s_waitcnt vmcnt(4)" ::: "memory")
#define SB0 __builtin_amdgcn_sched_barrier(0)
#define AS1 __attribute__((address_space(1)))
#define AS3 __attribute__((address_space(3)))

// ---------------- fused prep: x->bf16 cvt + both weight transposes ----------------
// [0,4096): cvt 16 elems/thread; [4096,7168): w_qkv^T; [7168,8192): w_proj^T
__global__ __launch_bounds__(256) void k_prep(const float* __restrict__ x,
                                              u16* __restrict__ xb,
                                              const float* __restrict__ wq,
                                              u16* __restrict__ wqT,
                                              const float* __restrict__ wp,
                                              u16* __restrict__ wpT) {
  const int bid = blockIdx.x;
  const int t = threadIdx.x;
  if (bid < 4096) {
    const int i = (bid * 256 + t) * 16;
    f32x4 v0 = *reinterpret_cast<const f32x4*>(x + i);
    f32x4 v1 = *reinterpret_cast<const f32x4*>(x + i + 4);
    f32x4 v2 = *reinterpret_cast<const f32x4*>(x + i + 8);
    f32x4 v3 = *reinterpret_cast<const f32x4*>(x + i + 12);
    u16x8 o0, o1;
#pragma unroll
    for (int j = 0; j < 4; ++j) {
      o0[j] = f2b(v0[j]); o0[4 + j] = f2b(v1[j]);
      o1[j] = f2b(v2[j]); o1[4 + j] = f2b(v3[j]);
    }
    *reinterpret_cast<u16x8*>(xb + i) = o0;
    *reinterpret_cast<u16x8*>(xb + i + 8) = o1;
    return;
  }
  // transpose path: fp32 [R][C] -> bf16 [C][R]
  const float* in; u16* out; int R, C, bx, by;
  if (bid < 7168) {
    const int b2 = bid - 4096;             // 96 x 32 tiles
    in = wq; out = wqT; R = 1024; C = 3072;
    bx = (b2 % 96) * 32; by = (b2 / 96) * 32;
  } else {
    const int b2 = bid - 7168;             // 32 x 32 tiles
    in = wp; out = wpT; R = 1024; C = 1024;
    bx = (b2 % 32) * 32; by = (b2 / 32) * 32;
  }
  __shared__ float tile[32][33];
  const int tx = t & 31, ty = t >> 5;      // (32,8)
#pragma unroll
  for (int i = 0; i < 32; i += 8)
    tile[ty + i][tx] = in[(size_t)(by + ty + i) * C + (bx + tx)];
  __syncthreads();
#pragma unroll
  for (int i = 0; i < 32; i += 8)
    out[(size_t)(bx + ty + i) * R + (by + tx)] = f2b(tile[tx][ty + i]);
}

// ---------------- 256x256 6-phase bf16 GEMM body (single tile) ----------------
// AMAP: A rows indirected through the dilated-Hilbert map (KV-GEMM reads xb
// directly; gather fused into the per-lane global_load_lds source address).
template <bool OUT_BF16, bool AMAP>
__device__ __forceinline__ void gemm_body(char* lds, const u16* __restrict__ A,
                                          const u16* __restrict__ Bt,
                                          const int* __restrict__ hmap,
                                          void* __restrict__ Cv,
                                          int N, int K, int gx, int bid) {
  const int tid = threadIdx.x;
  const int wid = tid >> 6, lane = tid & 63;
  const int wm = wid >> 2, wn = wid & 3;      // 2x4 wave grid
  const int lr = lane & 15, lq = lane >> 4;
  const int xr = (lr & 7) << 4;               // read-side XOR swizzle
  const int koff0 = (lq * 16) ^ xr;
  const int koff1 = (64 | (lq * 16)) ^ xr;

  // XCD-aware tile coord (256 tiles, cpx=32)
  const int swz = (bid & 7) * 32 + (bid >> 3);
  const int m0 = (swz / gx) * 256, n0 = (swz % gx) * 256;

  const int rowT = tid >> 3;                                        // 0..63
  const int colT = (((tid * 16) & 127) ^ ((rowT & 7) << 4)) >> 1;   // u16 units
  const size_t r64K = (size_t)64 * K;
  const size_t r128K = (size_t)128 * K;

  // four per-thread A row pointers (tile rows rowT, +64, +128, +192)
  const u16 *pA0, *pA1, *pA2, *pA3;
  if constexpr (AMAP) {
    auto maprow = [&](int gi) -> const u16* {
      const int token = hmap[((gi & 2047) >> 5) * 64 + 2 * (gi & 31)];
      return A + ((size_t)((gi >> 11) * 4096 + token)) * (size_t)K + colT;
    };
    pA0 = maprow(m0 + rowT);
    pA1 = maprow(m0 + 64 + rowT);
    pA2 = maprow(m0 + 128 + rowT);
    pA3 = maprow(m0 + 192 + rowT);
  } else {
    pA0 = A + (size_t)(m0 + rowT) * K + colT;
    pA1 = pA0 + r64K; pA2 = pA0 + r128K; pA3 = pA2 + r64K;
  }
  const u16* pBc = Bt + (size_t)(n0 + rowT) * K + colT;

  f32x4 acc[8][4];
  bf16x8 a[4][2];
  bf16x8 bb[2][2][2];

  auto LDS1 = [&](const u16* s0, int region) {
    __builtin_amdgcn_global_load_lds((const AS1 void*)s0,
                                     (AS3 void*)(lds + region + wid * 1024), 16, 0, 0);
  };
  auto STG_A0 = [&](int region, int k0) {   // tile rows 0-127
    LDS1(pA0 + k0, region); LDS1(pA1 + k0, region + 8192);
  };
  auto STG_A1 = [&](int region, int k0) {   // tile rows 128-255
    LDS1(pA2 + k0, region); LDS1(pA3 + k0, region + 8192);
  };
  auto STG_B = [&](int region, size_t hoff, int k0) {
    LDS1(pBc + hoff + k0, region); LDS1(pBc + hoff + r64K + k0, region + 8192);
  };
  auto rdA = [&](int dbuf, int mh) {
#pragma unroll
    for (int mi = 0; mi < 4; ++mi) {
      const int base = dbuf * 65536 + wm * 16384 + (mh * 64 + mi * 16 + lr) * 128;
      a[mi][0] = *(const bf16x8*)(lds + base + koff0);
      a[mi][1] = *(const bf16x8*)(lds + base + koff1);
    }
  };
  auto rdB = [&](int dbuf, int nh, int bset) {
#pragma unroll
    for (int ni = 0; ni < 2; ++ni) {
      const int base = dbuf * 65536 + 32768 + (wn >> 1) * 16384 +
                       ((wn & 1) * 64 + nh * 32 + ni * 16 + lr) * 128;
      bb[bset][ni][0] = *(const bf16x8*)(lds + base + koff0);
      bb[bset][ni][1] = *(const bf16x8*)(lds + base + koff1);
    }
  };
  auto mfma16 = [&](int mh, int nh, int bset) {
    __builtin_amdgcn_s_setprio(1);
#pragma unroll
    for (int kk = 0; kk < 2; ++kk)
#pragma unroll
      for (int ni = 0; ni < 2; ++ni)
#pragma unroll
        for (int mi = 0; mi < 4; ++mi)
          acc[mh * 4 + mi][nh * 2 + ni] = __builtin_amdgcn_mfma_f32_16x16x32_bf16(
              a[mi][kk], bb[bset][ni][kk], acc[mh * 4 + mi][nh * 2 + ni], 0, 0, 0);
    __builtin_amdgcn_s_setprio(0);
  };

  {
    f32x4 z = {0.f, 0.f, 0.f, 0.f};
#pragma unroll
    for (int i = 0; i < 8; ++i)
#pragma unroll
      for (int j = 0; j < 4; ++j) acc[i][j] = z;
  }

  // ---- prologue: buf0 all 4 halves @ k=0; buf1.B halves @ k=64 ----
  STG_A0(0, 0);
  STG_B(32768, 0, 0);
  STG_B(49152, r128K, 0);
  STG_A1(16384, 0);
  STG_B(65536 + 32768, 0, 64);
  STG_B(65536 + 49152, r128K, 64);
  WAIT_VM4; FENCE; BARRIER;

  const int NI = K >> 7;   // iterations of K=128

  for (int it = 0; it < NI; ++it) {
    const int kP1 = (2 * it + 1) * 64;
    const bool last = (it == NI - 1);
    const int kA = last ? 0 : (2 * it + 2) * 64;   // tail: dead self-restage
    const int kB = last ? 64 : (2 * it + 3) * 64;

    // P1
    rdA(0, 0); rdB(0, 0, 0);
    STG_A0(65536, kP1);
    FENCE; BARRIER; WAIT_LGKM0; SB0;
    mfma16(0, 0, 0);
    FENCE; BARRIER;
    // P2
    rdB(0, 1, 1);
    STG_A1(65536 + 16384, kP1);
    FENCE; BARRIER; WAIT_LGKM0; SB0;
    mfma16(0, 1, 1);
    FENCE; BARRIER;
    // P3' (merged)
    rdA(0, 1);
    STG_B(32768, 0, kA);
    STG_B(49152, r128K, kA);
    FENCE; BARRIER; WAIT_LGKM0; SB0;
    mfma16(1, 1, 1);
    mfma16(1, 0, 0);
    WAIT_VM4; FENCE; BARRIER;
    // P4'
    rdA(1, 0); rdB(1, 0, 0);
    STG_A0(0, kA);
    FENCE; BARRIER; WAIT_LGKM0; SB0;
    mfma16(0, 0, 0);
    FENCE; BARRIER;
    // P5'
    rdB(1, 1, 1);
    STG_A1(16384, kA);
    FENCE; BARRIER; WAIT_LGKM0; SB0;
    mfma16(0, 1, 1);
    FENCE; BARRIER;
    // P6' (merged)
    rdA(1, 1);
    STG_B(65536 + 32768, 0, kB);
    STG_B(65536 + 49152, r128K, kB);
    FENCE; BARRIER; WAIT_LGKM0; SB0;
    mfma16(1, 1, 1);
    mfma16(1, 0, 0);
    WAIT_VM4; FENCE; BARRIER;
  }

  // ---- epilogue ----
#pragma unroll
  for (int mi = 0; mi < 8; ++mi)
#pragma unroll
    for (int ni = 0; ni < 4; ++ni) {
      const int r0 = m0 + wm * 128 + (mi >> 2) * 64 + (mi & 3) * 16 + lq * 4;
      const int c = n0 + wn * 64 + (ni >> 1) * 32 + (ni & 1) * 16 + lr;
#pragma unroll
      for (int r = 0; r < 4; ++r) {
        const float v = acc[mi][ni][r];
        if (OUT_BF16)
          ((u16*)Cv)[(size_t)(r0 + r) * N + c] = f2b(v);
        else
          ((float*)Cv)[(size_t)(r0 + r) * N + c] = v;
      }
    }
}

// Q-GEMM (blocks 0-255, dense A) + KV-GEMM (blocks 256-511, hilbert-dilated A).
__global__ __launch_bounds__(512, 2) void k_gemm_qkv(const u16* __restrict__ xb,
                                                     const u16* __restrict__ wT,
                                                     const int* __restrict__ hmap,
                                                     u16* __restrict__ qb,
                                                     u16* __restrict__ kvb) {
  __shared__ __align__(16) char lds[131072];
  if (blockIdx.x >= 256)
    gemm_body<true, true>(lds, xb, wT + 1024 * 1024, hmap, kvb, 2048, 1024, 8,
                          blockIdx.x & 255);
  else
    gemm_body<true, false>(lds, xb, wT, nullptr, qb, 1024, 1024, 4, blockIdx.x);
}

__global__ __launch_bounds__(512, 2) void k_gemm_proj(const u16* __restrict__ A,
                                                      const u16* __restrict__ Bt,
                                                      float* __restrict__ C) {
  __shared__ __align__(16) char lds[131072];
  gemm_body<false, false>(lds, A, Bt, nullptr, C, 1024, 1024, 4, blockIdx.x);
}

// ---------------- segment attention: MFMA + in-register softmax ----------------
// Q gathered from qb (stride 1024); K/V dense from kvb (stride 2048, seg order).
__global__ __launch_bounds__(256) void k_attn2(const u16* __restrict__ qb,
                                               const u16* __restrict__ kvb,
                                               const int* __restrict__ hmap,
                                               u16* __restrict__ att) {
  __shared__ u16 VT[64 * 40];       // V^T[d][k], stride 40 u16, XOR-chunk swizzled
  __shared__ u16 Pl[4][16 * 40];    // per-wave P[16 q][32 k], stride 40 u16

  const int blk = blockIdx.x;
  const int b = blk >> 10, h = (blk >> 6) & 15, s = blk & 63;
  const int t = threadIdx.x, w = t >> 6, lane = t & 63;
  const int lr = lane & 15, lq = lane >> 4;
  const int* hm = hmap + s * 64;
  const size_t bb4 = (size_t)b * L_SEQ;
  const size_t kvrow0 = (size_t)(b * 2048 + s * 32);

  // ---- stage V^T (dense rows; XOR-chunk swizzle kills write conflicts) ----
  {
    const int kj = t >> 3, d0 = (t & 7) * 8;
    const u16* p = kvb + (kvrow0 + kj) * 2048 + 1024 + h * 64 + d0;
    u16x8 v = *(const u16x8*)p;
#pragma unroll
    for (int j = 0; j < 8; ++j) {
      const int d = d0 + j;
      const int chunk = (kj >> 3) ^ ((d >> 3) & 3);
      VT[d * 40 + chunk * 8 + (kj & 7)] = v[j];
    }
  }

  // ---- Q (gathered) / K (dense) fragments ----
  const u16* qp = qb + (bb4 + hm[16 * w + lr]) * 1024 + h * 64 + lq * 8;
  bf16x8 aq0 = *(const bf16x8*)(qp);
  bf16x8 aq1 = *(const bf16x8*)(qp + 32);
  bf16x8 bk[2][2];
#pragma unroll
  for (int nk = 0; nk < 2; ++nk) {
    const u16* kp = kvb + (kvrow0 + nk * 16 + lr) * 2048 + h * 64 + lq * 8;
    bk[nk][0] = *(const bf16x8*)(kp);
    bk[nk][1] = *(const bf16x8*)(kp + 32);
  }

  // ---- scores ----
  f32x4 z4 = {0.f, 0.f, 0.f, 0.f};
  f32x4 s0 = __builtin_amdgcn_mfma_f32_16x16x32_bf16(aq0, bk[0][0], z4, 0, 0, 0);
  s0 = __builtin_amdgcn_mfma_f32_16x16x32_bf16(aq1, bk[0][1], s0, 0, 0, 0);
  f32x4 s1 = __builtin_amdgcn_mfma_f32_16x16x32_bf16(aq0, bk[1][0], z4, 0, 0, 0);
  s1 = __builtin_amdgcn_mfma_f32_16x16x32_bf16(aq1, bk[1][1], s1, 0, 0, 0);

  // ---- in-register softmax (lr-group shuffle reduce) ----
  float inv[4];
  u16* Pw = Pl[w];
#pragma unroll
  for (int r = 0; r < 4; ++r) {
    float a0 = s0[r] * 0.125f, a1 = s1[r] * 0.125f;
    float m = fmaxf(a0, a1);
    m = fmaxf(m, __shfl_xor(m, 1));
    m = fmaxf(m, __shfl_xor(m, 2));
    m = fmaxf(m, __shfl_xor(m, 4));
    m = fmaxf(m, __shfl_xor(m, 8));
    float e0 = __expf(a0 - m), e1 = __expf(a1 - m);
    float sum = e0 + e1;
    sum += __shfl_xor(sum, 1);
    sum += __shfl_xor(sum, 2);
    sum += __shfl_xor(sum, 4);
    sum += __shfl_xor(sum, 8);
    inv[r] = 1.f / sum;
    Pw[(lq * 4 + r) * 40 + lr] = f2b(e0);
    Pw[(lq * 4 + r) * 40 + 16 + lr] = f2b(e1);
  }

  __syncthreads();

  // ---- PV ----
  bf16x8 ap = *(const bf16x8*)(Pw + lr * 40 + lq * 8);
  f32x4 o[4];
#pragma unroll
  for (int nd = 0; nd < 4; ++nd) {
    const int row = nd * 16 + lr;
    const int chunk = lq ^ ((row >> 3) & 3);
    bf16x8 bv = *(const bf16x8*)(VT + row * 40 + chunk * 8);
    o[nd] = __builtin_amdgcn_mfma_f32_16x16x32_bf16(ap, bv, z4, 0, 0, 0);
  }

  // ---- scatter back to original token order ----
#pragma unroll
  for (int r = 0; r < 4; ++r) {
    u16* dst = att + (bb4 + hm[16 * w + lq * 4 + r]) * 1024 + h * 64 + lr;
#pragma unroll
    for (int nd = 0; nd < 4; ++nd)
      dst[nd * 16] = f2b(o[nd][r] * inv[r]);
  }
}

extern "C" void kernel_launch(void* const* d_in, const int* in_sizes, int n_in,
                              void* d_out, int out_size, void* d_ws, size_t ws_size,
                              hipStream_t stream) {
  const float* x = (const float*)d_in[0];
  const float* w_qkv = (const float*)d_in[1];
  const float* w_proj = (const float*)d_in[2];
  const int* hmap = (const int*)d_in[3];
  float* out = (float*)d_out;

  char* ws = (char*)d_ws;
  u16* qb    = (u16*)(ws);                   // 16384*1024*2 = 33554432
  u16* kvb   = (u16*)(ws + 33554432ull);     //  8192*2048*2 = 33554432
  u16* xb    = (u16*)(ws + 67108864ull);     // 16384*1024*2 = 33554432 (att aliases)
  u16* wqkvT = (u16*)(ws + 100663296ull);    //  3072*1024*2 = 6291456
  u16* wpT   = (u16*)(ws + 106954752ull);    //  1024*1024*2 = 2097152  -> 109051904 total
  u16* att = xb;  // xb dead after gemm_qkv

  k_prep<<<8192, 256, 0, stream>>>(x, xb, w_qkv, wqkvT, w_proj, wpT);
  // Q-GEMM (256 blocks) + KV-GEMM (256 blocks, gather fused into A-staging)
  k_gemm_qkv<<<512, 512, 0, stream>>>(xb, wqkvT, hmap, qb, kvb);
  k_attn2<<<4096, 256, 0, stream>>>(qb, kvb, hmap, att);
  // out = att @ w_proj (fp32 out)
  k_gemm_proj<<<256, 512, 0, stream>>>(att, wpT, out);
}